// Round 2
// baseline (267.269 us; speedup 1.0000x reference)
//
#include <hip/hip_runtime.h>
#include <hip/hip_bf16.h>

// Sizes fixed by the problem.
#define BS    64
#define KDIM  256   // in_dim
#define ICAP  256   // I = 16*16
#define JCAP  64    // J out-caps
#define D2    32
#define OUTD  2048  // J*D2

typedef short bf16x8 __attribute__((ext_vector_type(8)));
typedef float f32x4  __attribute__((ext_vector_type(4)));

static __device__ __forceinline__ float bf2f(unsigned u16) {
  union { unsigned u; float f; } v; v.u = u16 << 16; return v.f;
}
static __device__ __forceinline__ unsigned short f2bf(float x) {
  union { float f; unsigned u; } v; v.f = x;
  unsigned r = v.u + 0x7fffu + ((v.u >> 16) & 1u);
  return (unsigned short)(r >> 16);
}
static __device__ __forceinline__ void unpack8(uint4 u, float* f) {
  f[0] = bf2f(u.x & 0xffffu); f[1] = bf2f(u.x >> 16);
  f[2] = bf2f(u.y & 0xffffu); f[3] = bf2f(u.y >> 16);
  f[4] = bf2f(u.z & 0xffffu); f[5] = bf2f(u.z >> 16);
  f[6] = bf2f(u.w & 0xffffu); f[7] = bf2f(u.w >> 16);
}

// ---------------------------------------------------------------------------
// Kernel 1: P[b][i][o] = sum_k W[o][k] * x[b][k][i]  + Wb[o]   (bf16 out)
// fp32 inputs converted to bf16 during LDS staging.
// Block tile: 64 o x 64 i, 4 waves (2x2 of 32x32), K staged in 2 halves of 128.
// ---------------------------------------------------------------------------
__global__ __launch_bounds__(256) void gemm_pred(
    const float* __restrict__ x,     // [BS][KDIM][ICAP] f32
    const float* __restrict__ W,     // [OUTD][KDIM] f32
    const float* __restrict__ Wb,    // [OUTD] f32
    unsigned short* __restrict__ P)  // [BS][ICAP][OUTD] bf16
{
  __shared__ unsigned short Ws[64][136];  // [o][k], pad->272B stride
  __shared__ unsigned short Xs[64][136];  // [i][k] transposed x tile
  __shared__ float Cs[64][68];            // [i][o] epilogue transpose

  const int tid = threadIdx.x;
  const int b  = blockIdx.z;
  const int o0 = blockIdx.x * 64;
  const int i0 = blockIdx.y * 64;
  const int l  = tid & 63;
  const int w  = tid >> 6;
  const int wo = (w & 1) * 32;
  const int wi = (w >> 1) * 32;

  f32x4 acc00 = {0.f,0.f,0.f,0.f};
  f32x4 acc01 = {0.f,0.f,0.f,0.f};
  f32x4 acc10 = {0.f,0.f,0.f,0.f};
  f32x4 acc11 = {0.f,0.f,0.f,0.f};

  const int m  = l & 15;
  const int q8 = (l >> 4) * 8;

  for (int kh = 0; kh < 2; ++kh) {
    const int k0 = kh * 128;
    __syncthreads();
    // stage W tile: 64 rows x 128 k, fp32 -> bf16
    {
      const int o_l = tid >> 2;
      const int c0  = tid & 3;
      const float* src = W + (o0 + o_l) * KDIM + k0;
      for (int c = c0; c < 16; c += 4) {
        f32x4 a = *(const f32x4*)(src + c * 8);
        f32x4 d = *(const f32x4*)(src + c * 8 + 4);
        uint4 s;
        s.x = (unsigned)f2bf(a.x) | ((unsigned)f2bf(a.y) << 16);
        s.y = (unsigned)f2bf(a.z) | ((unsigned)f2bf(a.w) << 16);
        s.z = (unsigned)f2bf(d.x) | ((unsigned)f2bf(d.y) << 16);
        s.w = (unsigned)f2bf(d.z) | ((unsigned)f2bf(d.w) << 16);
        *(uint4*)&Ws[o_l][c * 8] = s;
      }
    }
    // stage x tile transposed: Xs[i][k] = bf16(x[b][k0+k][i0+i])
    {
      const int i4  = (tid & 15) * 4;
      const int kk0 = tid >> 4;  // 0..15
      for (int k = kk0; k < 128; k += 16) {
        f32x4 v = *(const f32x4*)(x + ((size_t)(b * KDIM + k0 + k) * ICAP) + i0 + i4);
        Xs[i4 + 0][k] = f2bf(v.x);
        Xs[i4 + 1][k] = f2bf(v.y);
        Xs[i4 + 2][k] = f2bf(v.z);
        Xs[i4 + 3][k] = f2bf(v.w);
      }
    }
    __syncthreads();
    for (int ks = 0; ks < 4; ++ks) {
      const int kk = ks * 32 + q8;
      bf16x8 a0 = *(const bf16x8*)&Ws[wo + m][kk];
      bf16x8 a1 = *(const bf16x8*)&Ws[wo + 16 + m][kk];
      bf16x8 b0 = *(const bf16x8*)&Xs[wi + m][kk];
      bf16x8 b1 = *(const bf16x8*)&Xs[wi + 16 + m][kk];
      acc00 = __builtin_amdgcn_mfma_f32_16x16x32_bf16(a0, b0, acc00, 0, 0, 0);
      acc01 = __builtin_amdgcn_mfma_f32_16x16x32_bf16(a0, b1, acc01, 0, 0, 0);
      acc10 = __builtin_amdgcn_mfma_f32_16x16x32_bf16(a1, b0, acc10, 0, 0, 0);
      acc11 = __builtin_amdgcn_mfma_f32_16x16x32_bf16(a1, b1, acc11, 0, 0, 0);
    }
  }

  __syncthreads();
  // C/D layout: row(M=o) = (l>>4)*4 + r, col(N=i) = l&15  -> Cs[i][o]
  {
    const int q4 = (l >> 4) * 4;
    *(f32x4*)&Cs[wi +  0 + m][wo +  0 + q4] = acc00;
    *(f32x4*)&Cs[wi + 16 + m][wo +  0 + q4] = acc01;
    *(f32x4*)&Cs[wi +  0 + m][wo + 16 + q4] = acc10;
    *(f32x4*)&Cs[wi + 16 + m][wo + 16 + q4] = acc11;
  }
  __syncthreads();
  // epilogue: add fp32 bias, convert to bf16, coalesced stores (o contiguous)
  {
    const int r  = tid >> 2;        // i row 0..63
    const int oc = (tid & 3) * 16;  // o chunk
    f32x4 w0 = *(const f32x4*)(Wb + o0 + oc);
    f32x4 w1 = *(const f32x4*)(Wb + o0 + oc + 4);
    f32x4 w2 = *(const f32x4*)(Wb + o0 + oc + 8);
    f32x4 w3 = *(const f32x4*)(Wb + o0 + oc + 12);
    float wb[16] = {w0.x,w0.y,w0.z,w0.w, w1.x,w1.y,w1.z,w1.w,
                    w2.x,w2.y,w2.z,w2.w, w3.x,w3.y,w3.z,w3.w};
    unsigned pk[8];
    for (int c = 0; c < 8; ++c) {
      float lo = Cs[r][oc + 2 * c]     + wb[2 * c];
      float hi = Cs[r][oc + 2 * c + 1] + wb[2 * c + 1];
      pk[c] = (unsigned)f2bf(lo) | ((unsigned)f2bf(hi) << 16);
    }
    unsigned short* dst = P + ((size_t)(b * ICAP + i0 + r) * OUTD) + o0 + oc;
    uint4 s0; s0.x = pk[0]; s0.y = pk[1]; s0.z = pk[2]; s0.w = pk[3];
    uint4 s1; s1.x = pk[4]; s1.y = pk[5]; s1.z = pk[6]; s1.w = pk[7];
    *(uint4*)dst       = s0;
    *(uint4*)(dst + 8) = s1;
  }
}

// ---------------------------------------------------------------------------
// Kernel 2: one routing pass, fused db + b-update + softmax + s-accumulate.
// One wave per (b, 8-column chunk); lane l = out-cap j. No atomics.
// pass 0: c=softmax(b_init), s0.     pass 1: b1=b_init+v0·P, store b1, s1.
// pass 2: b2=b1+v1·P, s2.
// ---------------------------------------------------------------------------
__global__ __launch_bounds__(256) void route_pass(
    const unsigned short* __restrict__ P,  // [BS][ICAP][OUTD] bf16
    const float* __restrict__ Binit,       // [BS][JCAP][ICAP] f32
    float* __restrict__ B1,                // [BS][ICAP][JCAP] f32
    const float* __restrict__ V,           // [BS][JCAP][D2] f32
    float* __restrict__ partial,           // [BS][32][OUTD] f32
    const int pass)
{
  const int tid   = threadIdx.x;
  const int l     = tid & 63;                 // j
  const int b     = blockIdx.y;
  const int chunk = blockIdx.x * 4 + (tid >> 6);  // 0..31
  const int i0    = chunk * 8;

  float vv[32];
  if (pass > 0) {
    const float* vp = V + (b * JCAP + l) * D2;
    for (int q = 0; q < 8; ++q) {
      f32x4 t = *(const f32x4*)(vp + q * 4);
      vv[q*4+0] = t.x; vv[q*4+1] = t.y; vv[q*4+2] = t.z; vv[q*4+3] = t.w;
    }
  }
  float bold[8];
  if (pass <= 1) {
    const float* bp = Binit + (b * JCAP + l) * ICAP + i0;
    f32x4 t0 = *(const f32x4*)bp;
    f32x4 t1 = *(const f32x4*)(bp + 4);
    bold[0]=t0.x; bold[1]=t0.y; bold[2]=t0.z; bold[3]=t0.w;
    bold[4]=t1.x; bold[5]=t1.y; bold[6]=t1.z; bold[7]=t1.w;
  }

  float sacc[32];
  for (int k = 0; k < 32; ++k) sacc[k] = 0.f;

  for (int ii = 0; ii < 8; ++ii) {
    const int i = i0 + ii;
    const unsigned short* pc = P + ((size_t)(b * ICAP + i) * OUTD) + l * D2;
    float ps[32];
    for (int q = 0; q < 4; ++q) {
      uint4 u = *(const uint4*)(pc + q * 8);
      unpack8(u, ps + q * 8);
    }
    float bnew;
    if (pass == 0) {
      bnew = bold[ii];
    } else {
      float db = 0.f;
      for (int k = 0; k < 32; ++k) db += ps[k] * vv[k];
      float bo = (pass == 1) ? bold[ii] : B1[(b * ICAP + i) * JCAP + l];
      bnew = bo + db;
      if (pass == 1) B1[(b * ICAP + i) * JCAP + l] = bnew;
    }
    // softmax over the 64 lanes (= J)
    float mx = bnew;
    for (int off = 1; off < 64; off <<= 1) mx = fmaxf(mx, __shfl_xor(mx, off, 64));
    float e = __expf(bnew - mx);
    float se = e;
    for (int off = 1; off < 64; off <<= 1) se += __shfl_xor(se, off, 64);
    float c = e / se;
    for (int k = 0; k < 32; ++k) sacc[k] += c * ps[k];
  }

  float* pp = partial + ((size_t)(b * 32 + chunk) * OUTD) + l * D2;
  for (int q = 0; q < 8; ++q) {
    f32x4 t; t.x = sacc[q*4+0]; t.y = sacc[q*4+1]; t.z = sacc[q*4+2]; t.w = sacc[q*4+3];
    *(f32x4*)(pp + q * 4) = t;
  }
}

// ---------------------------------------------------------------------------
// Kernel 3: reduce partials over 32 chunks, squash, write V (and out if final).
// One wave per (b,j).
// ---------------------------------------------------------------------------
__global__ __launch_bounds__(256) void squash_k(
    const float* __restrict__ partial,   // [BS][32][OUTD]
    float* __restrict__ V,               // [BS][JCAP][D2]
    float* __restrict__ outp,            // [BS][JCAP][D2] f32
    const int final_pass)
{
  const int tid = threadIdx.x;
  const int l   = tid & 63;
  const int bj  = blockIdx.x * 4 + (tid >> 6);  // 0..4095
  const int b   = bj >> 6;
  const int j   = bj & 63;
  const int d   = l & 31;
  const int h   = l >> 5;

  float s = 0.f;
  for (int p = h; p < 32; p += 2)
    s += partial[((size_t)(b * 32 + p) * OUTD) + j * D2 + d];
  s += __shfl_xor(s, 32, 64);

  float sq = s * s;
  for (int off = 1; off < 32; off <<= 1) sq += __shfl_xor(sq, off, 64);

  float scale = (sq / (1.0f + sq)) / sqrtf(sq + 1e-8f);
  float v = scale * s;
  if (l < 32) {
    V[(b * JCAP + j) * D2 + d] = v;
    if (final_pass) outp[(b * JCAP + j) * D2 + d] = v;
  }
}

// ---------------------------------------------------------------------------
extern "C" void kernel_launch(void* const* d_in, const int* in_sizes, int n_in,
                              void* d_out, int out_size, void* d_ws, size_t ws_size,
                              hipStream_t stream) {
  const float* x  = (const float*)d_in[0];
  const float* bi = (const float*)d_in[1];
  const float* W  = (const float*)d_in[2];
  const float* Wb = (const float*)d_in[3];
  float* out = (float*)d_out;

  char* ws = (char*)d_ws;
  unsigned short* P  = (unsigned short*)ws;                          // 64 MiB
  float* partial     = (float*)(ws + (size_t)64 * 1024 * 1024);      // 16 MiB
  float* B1          = (float*)(ws + (size_t)80 * 1024 * 1024);      //  4 MiB
  float* V           = (float*)(ws + (size_t)84 * 1024 * 1024);      // 0.5 MiB

  gemm_pred<<<dim3(32, 4, 64), 256, 0, stream>>>(x, W, Wb, P);

  route_pass<<<dim3(8, 64), 256, 0, stream>>>(P, bi, B1, V, partial, 0);
  squash_k<<<dim3(1024), 256, 0, stream>>>(partial, V, out, 0);

  route_pass<<<dim3(8, 64), 256, 0, stream>>>(P, bi, B1, V, partial, 1);
  squash_k<<<dim3(1024), 256, 0, stream>>>(partial, V, out, 0);

  route_pass<<<dim3(8, 64), 256, 0, stream>>>(P, bi, B1, V, partial, 2);
  squash_k<<<dim3(1024), 256, 0, stream>>>(partial, V, out, 1);
}

// Round 3
// 193.727 us; speedup vs baseline: 1.3796x; 1.3796x over previous
//
#include <hip/hip_runtime.h>
#include <hip/hip_bf16.h>

// Sizes fixed by the problem.
#define BS    64
#define KDIM  256   // in_dim
#define ICAP  256   // I = 16*16
#define JCAP  64    // J out-caps
#define D2    32
#define OUTD  2048  // J*D2
#define PART  64    // partial-sum chunks (4 i per chunk)

typedef short bf16x8 __attribute__((ext_vector_type(8)));
typedef float f32x4  __attribute__((ext_vector_type(4)));

static __device__ __forceinline__ float bf2f(unsigned u16) {
  union { unsigned u; float f; } v; v.u = u16 << 16; return v.f;
}
static __device__ __forceinline__ unsigned short f2bf(float x) {
  union { float f; unsigned u; } v; v.f = x;
  unsigned r = v.u + 0x7fffu + ((v.u >> 16) & 1u);
  return (unsigned short)(r >> 16);
}
static __device__ __forceinline__ void unpack8(uint4 u, float* f) {
  f[0] = bf2f(u.x & 0xffffu); f[1] = bf2f(u.x >> 16);
  f[2] = bf2f(u.y & 0xffffu); f[3] = bf2f(u.y >> 16);
  f[4] = bf2f(u.z & 0xffffu); f[5] = bf2f(u.z >> 16);
  f[6] = bf2f(u.w & 0xffffu); f[7] = bf2f(u.w >> 16);
}

// ---------------------------------------------------------------------------
// Pre-kernel A: W f32 [OUTD][KDIM] -> bf16 same layout.
// ---------------------------------------------------------------------------
__global__ __launch_bounds__(256) void conv_w(
    const float* __restrict__ W, unsigned short* __restrict__ Wbf)
{
  const int g = blockIdx.x * 256 + threadIdx.x;   // 65536 threads, 8 elems each
  const float* s = W + (size_t)g * 8;
  f32x4 a = *(const f32x4*)s;
  f32x4 b = *(const f32x4*)(s + 4);
  uint4 o;
  o.x = (unsigned)f2bf(a.x) | ((unsigned)f2bf(a.y) << 16);
  o.y = (unsigned)f2bf(a.z) | ((unsigned)f2bf(a.w) << 16);
  o.z = (unsigned)f2bf(b.x) | ((unsigned)f2bf(b.y) << 16);
  o.w = (unsigned)f2bf(b.z) | ((unsigned)f2bf(b.w) << 16);
  *(uint4*)(Wbf + (size_t)g * 8) = o;
}

// ---------------------------------------------------------------------------
// Pre-kernel B: x f32 [b][k][i] -> xT bf16 [b][i][k], 64x64 LDS tile transpose.
// ---------------------------------------------------------------------------
__global__ __launch_bounds__(256) void transpose_x(
    const float* __restrict__ x, unsigned short* __restrict__ xT)
{
  __shared__ float Ls[64][65];
  const int t  = threadIdx.x;
  const int b  = blockIdx.z;
  const int k0 = blockIdx.y * 64;
  const int i0 = blockIdx.x * 64;

  for (int it = 0; it < 4; ++it) {
    const int k  = it * 16 + (t >> 4);
    const int i4 = (t & 15) * 4;
    f32x4 v = *(const f32x4*)(x + ((size_t)(b * KDIM + k0 + k) * ICAP) + i0 + i4);
    Ls[k][i4 + 0] = v.x; Ls[k][i4 + 1] = v.y;
    Ls[k][i4 + 2] = v.z; Ls[k][i4 + 3] = v.w;
  }
  __syncthreads();
  {
    const int i  = t >> 2;
    const int kc = (t & 3) * 16;
    unsigned pk[8];
    for (int q = 0; q < 8; ++q) {
      float lo = Ls[kc + 2 * q][i];
      float hi = Ls[kc + 2 * q + 1][i];
      pk[q] = (unsigned)f2bf(lo) | ((unsigned)f2bf(hi) << 16);
    }
    unsigned short* dst = xT + ((size_t)(b * ICAP + i0 + i) * KDIM) + k0 + kc;
    uint4 s0; s0.x = pk[0]; s0.y = pk[1]; s0.z = pk[2]; s0.w = pk[3];
    uint4 s1; s1.x = pk[4]; s1.y = pk[5]; s1.z = pk[6]; s1.w = pk[7];
    *(uint4*)dst       = s0;
    *(uint4*)(dst + 8) = s1;
  }
}

// ---------------------------------------------------------------------------
// Kernel 1: P[b][i][o] = sum_k W[o][k]*x[b][k][i] + Wb[o]  (bf16 out)
// Both operands pre-converted bf16, k-contiguous. 128x128 tile, 4 waves
// (each 64x64 = 4x4 MFMA 16x16x32), BK=64 x 4 rounds. LDS rows padded to 72
// (conflict-free b128 staging writes AND fragment reads). Epilogue transposes
// through overlaid LDS to [i][o], coalesced 256B row stores.
// ---------------------------------------------------------------------------
__global__ __launch_bounds__(256) void gemm_pred(
    const unsigned short* __restrict__ Wbf,  // [OUTD][KDIM] bf16
    const unsigned short* __restrict__ xT,   // [BS][ICAP][KDIM] bf16
    const float* __restrict__ Wb,            // [OUTD] f32
    unsigned short* __restrict__ P)          // [BS][ICAP][OUTD] bf16
{
  __shared__ union {
    unsigned short AB[2][128][72];   // [0]=W rows(o), [1]=xT rows(i); pad 72
    unsigned short C[128][136];      // [i][o] epilogue (stride 272B = 17*16)
  } sm;

  const int tid = threadIdx.x;
  const int b   = blockIdx.z;
  const int o0  = blockIdx.x * 128;
  const int i0  = blockIdx.y * 128;
  const int l   = tid & 63;
  const int m   = l & 15;
  const int q8  = (l >> 4) * 8;
  const int w   = tid >> 6;
  const int wo  = (w & 1) * 64;
  const int wi  = (w >> 1) * 64;

  f32x4 acc[4][4];
  for (int a = 0; a < 4; ++a)
    for (int c = 0; c < 4; ++c) acc[a][c] = (f32x4){0.f, 0.f, 0.f, 0.f};

  for (int r = 0; r < 4; ++r) {
    const int k0 = r * 64;
    __syncthreads();
    // stage: 1024 16B-chunks per tile; id -> (row, chunk); coalesced 128B rows
    for (int c = 0; c < 4; ++c) {
      const int id  = c * 256 + tid;
      const int row = id >> 3;
      const int ch  = id & 7;
      uint4 va = *(const uint4*)(Wbf + (size_t)(o0 + row) * KDIM + k0 + ch * 8);
      uint4 vb = *(const uint4*)(xT + ((size_t)(b * ICAP + i0 + row) * KDIM) + k0 + ch * 8);
      *(uint4*)&sm.AB[0][row][ch * 8] = va;
      *(uint4*)&sm.AB[1][row][ch * 8] = vb;
    }
    __syncthreads();
    for (int ks = 0; ks < 2; ++ks) {
      const int kk = ks * 32 + q8;
      bf16x8 af[4], bfg[4];
      for (int ti = 0; ti < 4; ++ti)
        af[ti] = *(const bf16x8*)&sm.AB[0][wo + 16 * ti + m][kk];
      for (int tj = 0; tj < 4; ++tj)
        bfg[tj] = *(const bf16x8*)&sm.AB[1][wi + 16 * tj + m][kk];
      for (int ti = 0; ti < 4; ++ti)
        for (int tj = 0; tj < 4; ++tj)
          acc[ti][tj] = __builtin_amdgcn_mfma_f32_16x16x32_bf16(
              af[ti], bfg[tj], acc[ti][tj], 0, 0, 0);
    }
  }

  __syncthreads();
  // D layout: row(M=o) = (l>>4)*4 + reg, col(N=i) = l&15. Write bf16 C[i][o].
  {
    const int q4 = (l >> 4) * 4;
    for (int ti = 0; ti < 4; ++ti) {
      const int ob = wo + 16 * ti + q4;
      f32x4 wb4 = *(const f32x4*)(Wb + o0 + ob);
      for (int tj = 0; tj < 4; ++tj) {
        const int ii = wi + 16 * tj + m;
        f32x4 a = acc[ti][tj];
        uint2 pk;
        pk.x = (unsigned)f2bf(a.x + wb4.x) | ((unsigned)f2bf(a.y + wb4.y) << 16);
        pk.y = (unsigned)f2bf(a.z + wb4.z) | ((unsigned)f2bf(a.w + wb4.w) << 16);
        *(uint2*)&sm.C[ii][ob] = pk;
      }
    }
  }
  __syncthreads();
  // coalesced write-out: 128 rows x 256B
  for (int rr = 0; rr < 8; ++rr) {
    const int id  = rr * 256 + tid;
    const int row = id >> 4;
    const int seg = id & 15;
    uint4 v = *(const uint4*)&sm.C[row][seg * 8];
    *(uint4*)(P + ((size_t)(b * ICAP + i0 + row) * OUTD) + o0 + seg * 8) = v;
  }
}

// ---------------------------------------------------------------------------
// Kernel 2: one routing pass, fused db + b-update + softmax + s-accumulate.
// One wave per (b, 4-i chunk) -> 4096 waves; lane = out-cap j. No atomics.
// ---------------------------------------------------------------------------
__global__ __launch_bounds__(256) void route_pass(
    const unsigned short* __restrict__ P,      // [BS][ICAP][OUTD] bf16
    const float* __restrict__ Binit,           // [BS][JCAP][ICAP] f32
    float* __restrict__ B1,                    // [BS][ICAP][JCAP] f32
    const float* __restrict__ V,               // [BS][JCAP][D2] f32
    unsigned short* __restrict__ partial,      // [BS][PART][OUTD] bf16
    const int pass)
{
  const int tid   = threadIdx.x;
  const int l     = tid & 63;                      // j
  const int b     = blockIdx.y;
  const int chunk = blockIdx.x * 4 + (tid >> 6);   // 0..63
  const int i0    = chunk * 4;

  float vv[32];
  if (pass > 0) {
    const float* vp = V + (b * JCAP + l) * D2;
    for (int q = 0; q < 8; ++q) {
      f32x4 t = *(const f32x4*)(vp + q * 4);
      vv[q*4+0] = t.x; vv[q*4+1] = t.y; vv[q*4+2] = t.z; vv[q*4+3] = t.w;
    }
  }
  float bold[4];
  if (pass <= 1) {
    f32x4 t = *(const f32x4*)(Binit + (size_t)(b * JCAP + l) * ICAP + i0);
    bold[0] = t.x; bold[1] = t.y; bold[2] = t.z; bold[3] = t.w;
  }
  float bprev[4];
  if (pass == 2) {
    for (int ii = 0; ii < 4; ++ii)
      bprev[ii] = B1[((size_t)(b * ICAP + i0 + ii)) * JCAP + l];
  }

  // issue all P loads up front (latency hiding)
  uint4 u[4][4];
  for (int ii = 0; ii < 4; ++ii) {
    const unsigned short* pc = P + ((size_t)(b * ICAP + i0 + ii) * OUTD) + l * D2;
    for (int q = 0; q < 4; ++q) u[ii][q] = *(const uint4*)(pc + q * 8);
  }

  float sacc[32];
  for (int k = 0; k < 32; ++k) sacc[k] = 0.f;

  for (int ii = 0; ii < 4; ++ii) {
    float ps[32];
    for (int q = 0; q < 4; ++q) unpack8(u[ii][q], ps + q * 8);
    float bnew;
    if (pass == 0) {
      bnew = bold[ii];
    } else {
      float db = 0.f;
      for (int k = 0; k < 32; ++k) db += ps[k] * vv[k];
      float bo = (pass == 1) ? bold[ii] : bprev[ii];
      bnew = bo + db;
      if (pass == 1) B1[((size_t)(b * ICAP + i0 + ii)) * JCAP + l] = bnew;
    }
    // softmax over 64 lanes (= J)
    float mx = bnew;
    for (int off = 1; off < 64; off <<= 1) mx = fmaxf(mx, __shfl_xor(mx, off, 64));
    float e = __expf(bnew - mx);
    float se = e;
    for (int off = 1; off < 64; off <<= 1) se += __shfl_xor(se, off, 64);
    float c = e / se;
    for (int k = 0; k < 32; ++k) sacc[k] += c * ps[k];
  }

  unsigned short* pp = partial + ((size_t)(b * PART + chunk) * OUTD) + l * D2;
  for (int q = 0; q < 4; ++q) {
    uint4 o;
    o.x = (unsigned)f2bf(sacc[q*8+0]) | ((unsigned)f2bf(sacc[q*8+1]) << 16);
    o.y = (unsigned)f2bf(sacc[q*8+2]) | ((unsigned)f2bf(sacc[q*8+3]) << 16);
    o.z = (unsigned)f2bf(sacc[q*8+4]) | ((unsigned)f2bf(sacc[q*8+5]) << 16);
    o.w = (unsigned)f2bf(sacc[q*8+6]) | ((unsigned)f2bf(sacc[q*8+7]) << 16);
    *(uint4*)(pp + q * 8) = o;
  }
}

// ---------------------------------------------------------------------------
// Kernel 3: reduce PART partials, squash, write V (and out if final).
// One wave per (b,j).
// ---------------------------------------------------------------------------
__global__ __launch_bounds__(256) void squash_k(
    const unsigned short* __restrict__ partial,  // [BS][PART][OUTD] bf16
    float* __restrict__ V,                       // [BS][JCAP][D2] f32
    float* __restrict__ outp,                    // [BS][JCAP][D2] f32
    const int final_pass)
{
  const int tid = threadIdx.x;
  const int l   = tid & 63;
  const int bj  = blockIdx.x * 4 + (tid >> 6);  // 0..4095
  const int b   = bj >> 6;
  const int j   = bj & 63;
  const int d   = l & 31;
  const int h   = l >> 5;

  float s = 0.f;
  for (int p = h; p < PART; p += 2)
    s += bf2f(partial[((size_t)(b * PART + p) * OUTD) + j * D2 + d]);
  s += __shfl_xor(s, 32, 64);

  float sq = s * s;
  for (int off = 1; off < 32; off <<= 1) sq += __shfl_xor(sq, off, 64);

  float scale = (sq / (1.0f + sq)) / sqrtf(sq + 1e-8f);
  float v = scale * s;
  if (l < 32) {
    V[(b * JCAP + j) * D2 + d] = v;
    if (final_pass) outp[(b * JCAP + j) * D2 + d] = v;
  }
}

// ---------------------------------------------------------------------------
extern "C" void kernel_launch(void* const* d_in, const int* in_sizes, int n_in,
                              void* d_out, int out_size, void* d_ws, size_t ws_size,
                              hipStream_t stream) {
  const float* x  = (const float*)d_in[0];
  const float* bi = (const float*)d_in[1];
  const float* W  = (const float*)d_in[2];
  const float* Wb = (const float*)d_in[3];
  float* out = (float*)d_out;

  char* ws = (char*)d_ws;
  const size_t MiB = 1024 * 1024;
  unsigned short* P       = (unsigned short*)ws;                 // [0,64) MiB
  // xT/Wbf live only until gemm_pred completes; partial (written later)
  // overlays them to keep total workspace at 84.5 MiB.
  unsigned short* xT      = (unsigned short*)(ws + 64 * MiB);    // [64,72) MiB
  unsigned short* Wbf     = (unsigned short*)(ws + 72 * MiB);    // [72,73) MiB
  unsigned short* partial = (unsigned short*)(ws + 64 * MiB);    // [64,80) MiB (overlay)
  float* B1               = (float*)(ws + 80 * MiB);             // [80,84) MiB
  float* V                = (float*)(ws + 84 * MiB);             // 0.5 MiB

  conv_w<<<dim3(256), 256, 0, stream>>>(W, Wbf);
  transpose_x<<<dim3(4, 4, 64), 256, 0, stream>>>(x, xT);
  gemm_pred<<<dim3(16, 2, 64), 256, 0, stream>>>(Wbf, xT, Wb, P);

  route_pass<<<dim3(16, 64), 256, 0, stream>>>(P, bi, B1, V, partial, 0);
  squash_k<<<dim3(1024), 256, 0, stream>>>(partial, V, out, 0);

  route_pass<<<dim3(16, 64), 256, 0, stream>>>(P, bi, B1, V, partial, 1);
  squash_k<<<dim3(1024), 256, 0, stream>>>(partial, V, out, 0);

  route_pass<<<dim3(16, 64), 256, 0, stream>>>(P, bi, B1, V, partial, 2);
  squash_k<<<dim3(1024), 256, 0, stream>>>(partial, V, out, 1);
}

// Round 4
// 175.592 us; speedup vs baseline: 1.5221x; 1.1033x over previous
//
#include <hip/hip_runtime.h>
#include <hip/hip_bf16.h>

// Sizes fixed by the problem.
#define BS    64
#define KDIM  256   // in_dim
#define ICAP  256   // I = 16*16
#define JCAP  64    // J out-caps
#define D2    32
#define OUTD  2048  // J*D2
#define PART  64    // partial-sum chunks for route passes (4 i per chunk)

typedef short bf16x8 __attribute__((ext_vector_type(8)));
typedef float f32x4  __attribute__((ext_vector_type(4)));

static __device__ __forceinline__ float bf2f(unsigned u16) {
  union { unsigned u; float f; } v; v.u = u16 << 16; return v.f;
}
static __device__ __forceinline__ unsigned short f2bf(float x) {
  union { float f; unsigned u; } v; v.f = x;
  unsigned r = v.u + 0x7fffu + ((v.u >> 16) & 1u);
  return (unsigned short)(r >> 16);
}
static __device__ __forceinline__ void unpack8(uint4 u, float* f) {
  f[0] = bf2f(u.x & 0xffffu); f[1] = bf2f(u.x >> 16);
  f[2] = bf2f(u.y & 0xffffu); f[3] = bf2f(u.y >> 16);
  f[4] = bf2f(u.z & 0xffffu); f[5] = bf2f(u.z >> 16);
  f[6] = bf2f(u.w & 0xffffu); f[7] = bf2f(u.w >> 16);
}
// async global->LDS, 16B per lane; LDS dest = wave-uniform base + lane*16
static __device__ __forceinline__ void gl_lds16(const unsigned short* g,
                                                unsigned short* l) {
  __builtin_amdgcn_global_load_lds(
      (const __attribute__((address_space(1))) unsigned int*)g,
      (__attribute__((address_space(3))) unsigned int*)l, 16, 0, 0);
}

// ---------------------------------------------------------------------------
// Pre-kernel A: W f32 [OUTD][KDIM] -> bf16 same layout.
// ---------------------------------------------------------------------------
__global__ __launch_bounds__(256) void conv_w(
    const float* __restrict__ W, unsigned short* __restrict__ Wbf)
{
  const int g = blockIdx.x * 256 + threadIdx.x;
  const float* s = W + (size_t)g * 8;
  f32x4 a = *(const f32x4*)s;
  f32x4 b = *(const f32x4*)(s + 4);
  uint4 o;
  o.x = (unsigned)f2bf(a.x) | ((unsigned)f2bf(a.y) << 16);
  o.y = (unsigned)f2bf(a.z) | ((unsigned)f2bf(a.w) << 16);
  o.z = (unsigned)f2bf(b.x) | ((unsigned)f2bf(b.y) << 16);
  o.w = (unsigned)f2bf(b.z) | ((unsigned)f2bf(b.w) << 16);
  *(uint4*)(Wbf + (size_t)g * 8) = o;
}

// ---------------------------------------------------------------------------
// Pre-kernel B: x f32 [b][k][i] -> xT bf16 [b][i][k], 64x64 LDS tile transpose.
// ---------------------------------------------------------------------------
__global__ __launch_bounds__(256) void transpose_x(
    const float* __restrict__ x, unsigned short* __restrict__ xT)
{
  __shared__ float Ls[64][65];
  const int t  = threadIdx.x;
  const int b  = blockIdx.z;
  const int k0 = blockIdx.y * 64;
  const int i0 = blockIdx.x * 64;

  for (int it = 0; it < 4; ++it) {
    const int k  = it * 16 + (t >> 4);
    const int i4 = (t & 15) * 4;
    f32x4 v = *(const f32x4*)(x + ((size_t)(b * KDIM + k0 + k) * ICAP) + i0 + i4);
    Ls[k][i4 + 0] = v.x; Ls[k][i4 + 1] = v.y;
    Ls[k][i4 + 2] = v.z; Ls[k][i4 + 3] = v.w;
  }
  __syncthreads();
  {
    const int i  = t >> 2;
    const int kc = (t & 3) * 16;
    unsigned pk[8];
    for (int q = 0; q < 8; ++q) {
      float lo = Ls[kc + 2 * q][i];
      float hi = Ls[kc + 2 * q + 1][i];
      pk[q] = (unsigned)f2bf(lo) | ((unsigned)f2bf(hi) << 16);
    }
    unsigned short* dst = xT + ((size_t)(b * ICAP + i0 + i) * KDIM) + k0 + kc;
    uint4 s0; s0.x = pk[0]; s0.y = pk[1]; s0.z = pk[2]; s0.w = pk[3];
    uint4 s1; s1.x = pk[4]; s1.y = pk[5]; s1.z = pk[6]; s1.w = pk[7];
    *(uint4*)dst       = s0;
    *(uint4*)(dst + 8) = s1;
  }
}

// ---------------------------------------------------------------------------
// Pre-kernel C: c0[b][i][j] = softmax_j(b_init[b][j][i])  (bf16 out)
// One block per b; b_init row-staged in LDS, per-thread softmax over j.
// ---------------------------------------------------------------------------
__global__ __launch_bounds__(256) void softmax_c0(
    const float* __restrict__ Binit,     // [BS][JCAP][ICAP] f32
    unsigned short* __restrict__ c0)     // [BS][ICAP][JCAP] bf16
{
  __shared__ float Bs[64][260];
  const int t = threadIdx.x;
  const int b = blockIdx.x;

  for (int rep = 0; rep < 16; ++rep) {
    const int id = rep * 256 + t;
    const int j  = id >> 6;
    const int i4 = (id & 63) * 4;
    f32x4 v = *(const f32x4*)(Binit + ((size_t)(b * JCAP + j) * ICAP) + i4);
    *(f32x4*)&Bs[j][i4] = v;
  }
  __syncthreads();
  const int i = t;
  float m = -3.0e38f;
  for (int j = 0; j < 64; ++j) m = fmaxf(m, Bs[j][i]);
  float se = 0.f;
  for (int j = 0; j < 64; ++j) se += __expf(Bs[j][i] - m);
  const float inv = 1.0f / se;
  unsigned short* dst = c0 + ((size_t)(b * ICAP + i) * JCAP);
  for (int q = 0; q < 8; ++q) {
    unsigned pk[4];
    for (int h = 0; h < 4; ++h) {
      float lo = __expf(Bs[q * 8 + 2 * h][i] - m) * inv;
      float hi = __expf(Bs[q * 8 + 2 * h + 1][i] - m) * inv;
      pk[h] = (unsigned)f2bf(lo) | ((unsigned)f2bf(hi) << 16);
    }
    uint4 s; s.x = pk[0]; s.y = pk[1]; s.z = pk[2]; s.w = pk[3];
    *(uint4*)(dst + q * 8) = s;
  }
}

// ---------------------------------------------------------------------------
// Kernel 1: P[b][i][o] = sum_k W[o][k]*x[b][k][i] + Wb[o]  (bf16 out)
// + fused routing-pass-0 s-accumulation: s0part[b][iblk*2+h][o] using c0.
// Staging: global_load_lds width 16 into XOR-swizzled unpadded LDS tiles
// (chunk' = chunk ^ (row&7)); fragment ds_read_b128 is <=2-way on banks.
// ---------------------------------------------------------------------------
__global__ __launch_bounds__(256) void gemm_pred(
    const unsigned short* __restrict__ Wbf,  // [OUTD][KDIM] bf16
    const unsigned short* __restrict__ xT,   // [BS][ICAP][KDIM] bf16
    const float* __restrict__ Wb,            // [OUTD] f32
    const unsigned short* __restrict__ c0,   // [BS][ICAP][JCAP] bf16
    unsigned short* __restrict__ P,          // [BS][ICAP][OUTD] bf16
    float* __restrict__ s0part)              // [BS][4][OUTD] f32
{
  __shared__ union {
    unsigned short AB[2][128][64];           // swizzled, unpadded (32 KiB)
    struct {
      unsigned short C[128][136];            // [i][o] epilogue (272B stride)
      unsigned short c0t[128][4];            // c0 tile for this block's 4 j
    } ep;
  } sm;

  const int tid = threadIdx.x;
  const int b   = blockIdx.z;
  const int o0  = blockIdx.x * 128;
  const int i0  = blockIdx.y * 128;
  const int l   = tid & 63;
  const int m   = l & 15;
  const int w   = tid >> 6;
  const int wo  = (w & 1) * 64;
  const int wi  = (w >> 1) * 64;

  // staging geometry (per wave, per call q = w*4+c): covers rows q*8..q*8+7
  const int srow = l >> 3;                       // 0..7 row within octet
  const int gch  = (l & 7) ^ srow;               // swizzled global chunk
  const int q8   = (l >> 4) * 8;

  f32x4 acc[4][4];
  for (int a = 0; a < 4; ++a)
    for (int c = 0; c < 4; ++c) acc[a][c] = (f32x4){0.f, 0.f, 0.f, 0.f};

  for (int r = 0; r < 4; ++r) {
    const int k0 = r * 64;
    __syncthreads();
    for (int c = 0; c < 4; ++c) {
      const int q   = w * 4 + c;
      const int row = q * 8 + srow;
      gl_lds16(Wbf + (size_t)(o0 + row) * KDIM + k0 + gch * 8,
               &sm.AB[0][q * 8][0]);
      gl_lds16(xT + ((size_t)(b * ICAP + i0 + row) * KDIM) + k0 + gch * 8,
               &sm.AB[1][q * 8][0]);
    }
    __syncthreads();
    for (int ks = 0; ks < 2; ++ks) {
      const int clog = ks * 4 + (l >> 4);        // logical 16B chunk 0..7
      bf16x8 af[4], bfg[4];
      for (int ti = 0; ti < 4; ++ti) {
        const int row = wo + 16 * ti + m;
        af[ti] = *(const bf16x8*)&sm.AB[0][row][(clog ^ (m & 7)) * 8];
      }
      for (int tj = 0; tj < 4; ++tj) {
        const int row = wi + 16 * tj + m;
        bfg[tj] = *(const bf16x8*)&sm.AB[1][row][(clog ^ (m & 7)) * 8];
      }
      for (int ti = 0; ti < 4; ++ti)
        for (int tj = 0; tj < 4; ++tj)
          acc[ti][tj] = __builtin_amdgcn_mfma_f32_16x16x32_bf16(
              af[ti], bfg[tj], acc[ti][tj], 0, 0, 0);
    }
  }

  __syncthreads();
  // D layout: row(M=o) = (l>>4)*4 + reg, col(N=i) = l&15. Write bf16 C[i][o].
  {
    const int q4 = (l >> 4) * 4;
    for (int ti = 0; ti < 4; ++ti) {
      const int ob = wo + 16 * ti + q4;
      f32x4 wb4 = *(const f32x4*)(Wb + o0 + ob);
      for (int tj = 0; tj < 4; ++tj) {
        const int ii = wi + 16 * tj + m;
        f32x4 a = acc[ti][tj];
        uint2 pk;
        pk.x = (unsigned)f2bf(a.x + wb4.x) | ((unsigned)f2bf(a.y + wb4.y) << 16);
        pk.y = (unsigned)f2bf(a.z + wb4.z) | ((unsigned)f2bf(a.w + wb4.w) << 16);
        *(uint2*)&sm.ep.C[ii][ob] = pk;
      }
    }
  }
  // load this block's c0 tile: 128 i x 4 j (j0 = o0/32)
  if (tid < 128) {
    const int j0 = blockIdx.x * 4;
    uint2 v = *(const uint2*)(c0 + ((size_t)(b * ICAP + i0 + tid) * JCAP) + j0);
    *(uint2*)&sm.ep.c0t[tid][0] = v;
  }
  __syncthreads();
  // coalesced write-out: 128 rows x 256B
  for (int rr = 0; rr < 8; ++rr) {
    const int id  = rr * 256 + tid;
    const int row = id >> 4;
    const int seg = id & 15;
    uint4 v = *(const uint4*)&sm.ep.C[row][seg * 8];
    *(uint4*)(P + ((size_t)(b * ICAP + i0 + row) * OUTD) + o0 + seg * 8) = v;
  }
  // fused pass-0 s-accumulation: s0part[b][iblk*2+h][o0+oc] = sum_i c0*C
  {
    const int oc = tid & 127;          // local o
    const int h  = tid >> 7;           // i half
    const int jj = oc >> 5;            // local j (0..3)
    float s = 0.f;
    for (int ii = 0; ii < 64; ++ii) {
      const int i = h * 64 + ii;
      s += bf2f(sm.ep.C[i][oc]) * bf2f(sm.ep.c0t[i][jj]);
    }
    const int p = blockIdx.y * 2 + h;
    s0part[((size_t)(b * 4 + p) * OUTD) + o0 + oc] = s;
  }
}

// ---------------------------------------------------------------------------
// squash0: reduce 4 s0 partials, squash -> V (= v1). One wave per (b,j).
// ---------------------------------------------------------------------------
__global__ __launch_bounds__(256) void squash0(
    const float* __restrict__ s0part,    // [BS][4][OUTD] f32
    float* __restrict__ V)               // [BS][JCAP][D2] f32
{
  const int tid = threadIdx.x;
  const int l   = tid & 63;
  const int bj  = blockIdx.x * 4 + (tid >> 6);
  const int b   = bj >> 6;
  const int j   = bj & 63;
  const int d   = l & 31;
  const int h   = l >> 5;

  float s = 0.f;
  for (int p = h; p < 4; p += 2)
    s += s0part[((size_t)(b * 4 + p) * OUTD) + j * D2 + d];
  s += __shfl_xor(s, 32, 64);

  float sq = s * s;
  for (int off = 1; off < 32; off <<= 1) sq += __shfl_xor(sq, off, 64);
  float scale = (sq / (1.0f + sq)) / sqrtf(sq + 1e-8f);
  if (l < 32) V[(b * JCAP + j) * D2 + d] = scale * s;
}

// ---------------------------------------------------------------------------
// Kernel 2: routing pass t>=1, fused db + b-update + softmax + s-accumulate.
// One wave per (b, 4-i chunk) -> 4096 waves; lane = out-cap j. No atomics.
// pass 1: b1 = b_init + v1*P (store B1), s2.   pass 2: b2 = B1 + v2*P, s3.
// ---------------------------------------------------------------------------
__global__ __launch_bounds__(256) void route_pass(
    const unsigned short* __restrict__ P,      // [BS][ICAP][OUTD] bf16
    const float* __restrict__ Binit,           // [BS][JCAP][ICAP] f32
    float* __restrict__ B1,                    // [BS][ICAP][JCAP] f32
    const float* __restrict__ V,               // [BS][JCAP][D2] f32
    unsigned short* __restrict__ partial,      // [BS][PART][OUTD] bf16
    const int pass)
{
  const int tid   = threadIdx.x;
  const int l     = tid & 63;                      // j
  const int b     = blockIdx.y;
  const int chunk = blockIdx.x * 4 + (tid >> 6);   // 0..63
  const int i0    = chunk * 4;

  float vv[32];
  {
    const float* vp = V + (b * JCAP + l) * D2;
    for (int q = 0; q < 8; ++q) {
      f32x4 t = *(const f32x4*)(vp + q * 4);
      vv[q*4+0] = t.x; vv[q*4+1] = t.y; vv[q*4+2] = t.z; vv[q*4+3] = t.w;
    }
  }
  float bold[4];
  if (pass == 1) {
    f32x4 t = *(const f32x4*)(Binit + (size_t)(b * JCAP + l) * ICAP + i0);
    bold[0] = t.x; bold[1] = t.y; bold[2] = t.z; bold[3] = t.w;
  } else {
    for (int ii = 0; ii < 4; ++ii)
      bold[ii] = B1[((size_t)(b * ICAP + i0 + ii)) * JCAP + l];
  }

  uint4 u[4][4];
  for (int ii = 0; ii < 4; ++ii) {
    const unsigned short* pc = P + ((size_t)(b * ICAP + i0 + ii) * OUTD) + l * D2;
    for (int q = 0; q < 4; ++q) u[ii][q] = *(const uint4*)(pc + q * 8);
  }

  float sacc[32];
  for (int k = 0; k < 32; ++k) sacc[k] = 0.f;

  for (int ii = 0; ii < 4; ++ii) {
    float ps[32];
    for (int q = 0; q < 4; ++q) unpack8(u[ii][q], ps + q * 8);
    float db = 0.f;
    for (int k = 0; k < 32; ++k) db += ps[k] * vv[k];
    float bnew = bold[ii] + db;
    if (pass == 1) B1[((size_t)(b * ICAP + i0 + ii)) * JCAP + l] = bnew;
    // softmax over 64 lanes (= J)
    float mx = bnew;
    for (int off = 1; off < 64; off <<= 1) mx = fmaxf(mx, __shfl_xor(mx, off, 64));
    float e = __expf(bnew - mx);
    float se = e;
    for (int off = 1; off < 64; off <<= 1) se += __shfl_xor(se, off, 64);
    float c = e / se;
    for (int k = 0; k < 32; ++k) sacc[k] += c * ps[k];
  }

  unsigned short* pp = partial + ((size_t)(b * PART + chunk) * OUTD) + l * D2;
  for (int q = 0; q < 4; ++q) {
    uint4 o;
    o.x = (unsigned)f2bf(sacc[q*8+0]) | ((unsigned)f2bf(sacc[q*8+1]) << 16);
    o.y = (unsigned)f2bf(sacc[q*8+2]) | ((unsigned)f2bf(sacc[q*8+3]) << 16);
    o.z = (unsigned)f2bf(sacc[q*8+4]) | ((unsigned)f2bf(sacc[q*8+5]) << 16);
    o.w = (unsigned)f2bf(sacc[q*8+6]) | ((unsigned)f2bf(sacc[q*8+7]) << 16);
    *(uint4*)(pp + q * 8) = o;
  }
}

// ---------------------------------------------------------------------------
// Kernel 3: reduce PART partials, squash, write V (and out if final).
// ---------------------------------------------------------------------------
__global__ __launch_bounds__(256) void squash_k(
    const unsigned short* __restrict__ partial,  // [BS][PART][OUTD] bf16
    float* __restrict__ V,                       // [BS][JCAP][D2] f32
    float* __restrict__ outp,                    // [BS][JCAP][D2] f32
    const int final_pass)
{
  const int tid = threadIdx.x;
  const int l   = tid & 63;
  const int bj  = blockIdx.x * 4 + (tid >> 6);
  const int b   = bj >> 6;
  const int j   = bj & 63;
  const int d   = l & 31;
  const int h   = l >> 5;

  float s = 0.f;
  for (int p = h; p < PART; p += 2)
    s += bf2f(partial[((size_t)(b * PART + p) * OUTD) + j * D2 + d]);
  s += __shfl_xor(s, 32, 64);

  float sq = s * s;
  for (int off = 1; off < 32; off <<= 1) sq += __shfl_xor(sq, off, 64);
  float scale = (sq / (1.0f + sq)) / sqrtf(sq + 1e-8f);
  float v = scale * s;
  if (l < 32) {
    V[(b * JCAP + j) * D2 + d] = v;
    if (final_pass) outp[(b * JCAP + j) * D2 + d] = v;
  }
}

// ---------------------------------------------------------------------------
extern "C" void kernel_launch(void* const* d_in, const int* in_sizes, int n_in,
                              void* d_out, int out_size, void* d_ws, size_t ws_size,
                              hipStream_t stream) {
  const float* x  = (const float*)d_in[0];
  const float* bi = (const float*)d_in[1];
  const float* W  = (const float*)d_in[2];
  const float* Wb = (const float*)d_in[3];
  float* out = (float*)d_out;

  char* ws = (char*)d_ws;
  const size_t MiB = 1024 * 1024;
  unsigned short* P       = (unsigned short*)ws;               // [0,64) MiB
  // lifetimes: xT/Wbf/c0/s0part die once squash0 completes; partial (route
  // passes) overlays the whole [64,80) region afterwards.
  unsigned short* xT      = (unsigned short*)(ws + 64 * MiB);  // [64,72)
  unsigned short* Wbf     = (unsigned short*)(ws + 72 * MiB);  // [72,73)
  unsigned short* c0      = (unsigned short*)(ws + 76 * MiB);  // [76,78) bf16
  float*          s0part  = (float*)(ws + 78 * MiB);           // [78,80) f32
  unsigned short* partial = (unsigned short*)(ws + 64 * MiB);  // [64,80) overlay
  float* B1               = (float*)(ws + 80 * MiB);           // [80,84)
  float* V                = (float*)(ws + 84 * MiB);           // 0.5 MiB

  conv_w<<<dim3(256), 256, 0, stream>>>(W, Wbf);
  transpose_x<<<dim3(4, 4, 64), 256, 0, stream>>>(x, xT);
  softmax_c0<<<dim3(64), 256, 0, stream>>>(bi, c0);
  gemm_pred<<<dim3(16, 2, 64), 256, 0, stream>>>(Wbf, xT, Wb, c0, P, s0part);
  squash0<<<dim3(1024), 256, 0, stream>>>(s0part, V);

  route_pass<<<dim3(16, 64), 256, 0, stream>>>(P, bi, B1, V, partial, 1);
  squash_k<<<dim3(1024), 256, 0, stream>>>(partial, V, out, 0);

  route_pass<<<dim3(16, 64), 256, 0, stream>>>(P, bi, B1, V, partial, 2);
  squash_k<<<dim3(1024), 256, 0, stream>>>(partial, V, out, 1);
}